// Round 10
// baseline (488.690 us; speedup 1.0000x reference)
//
#include <hip/hip_runtime.h>

// RANGE2BEV: scatter range-view features (B,C,RH,RW) into BEV grid (B,C,D,W,H)
// with last-write-wins duplicate resolution (np fancy-assignment semantics).
//
//   pass 1: hipMemsetAsync winner = 0xFF (-1)
//   pass 2: per point, atomicMax(winner, i)   (largest point index wins)
//   pass 3: transpose feat (b,c,n) -> featT (b,n,c)   [float4 both sides]
//   pass 4: block = (b, c, 64000-cell chunk), NO LDS: per wave-iter load 64
//           winners, gather featT[w*64+c] ONLY for valid lanes (~11%),
//           nt-store 256 B contiguous. 3 memory instrs / 64 cells.

namespace {

typedef float v4f __attribute__((ext_vector_type(4)));

constexpr int Wg    = 400;          // (40-(-40))/0.2
constexpr int Hg    = 352;          // (70.4-0)/0.2
constexpr int Dg    = 5;            // (1-(-3))/0.8
constexpr int NCELL = Dg * Wg * Hg; // 704000
constexpr int NPTS  = 64 * 2048;    // 131072 points per batch
constexpr int CC    = 64;
constexpr int BB    = 2;
constexpr int Q     = 11;           // chunks per (b,c); CPC divisible by 256
constexpr int CPC   = NCELL / Q;    // 64000 cells per chunk

__global__ void scatter_winner_k(const float* __restrict__ xyz,
                                 int* __restrict__ winner) {
    int idx = blockIdx.x * blockDim.x + threadIdx.x;
    if (idx >= BB * NPTS) return;
    int b = idx >> 17;              // / NPTS (131072)
    int i = idx & (NPTS - 1);
    const float* base = xyz + (size_t)b * 3 * NPTS;
    float xp = base[i];
    float yp = base[NPTS + i];
    float zp = base[2 * NPTS + i];
    if (!(zp >= -3.0f && zp < 1.0f)) return;          // valid z: [-3, 1)
    int zbin  = (int)floorf((zp + 3.0f) / 0.8f);      // [0,4], same f32 math as ref
    int x_img = (int)(-yp / 0.2f) + 200;              // trunc-toward-zero, f32 div
    int y_img = (int)(-xp / 0.2f) + 352;
    x_img = min(max(x_img, 0), Wg - 1);
    y_img = min(max(y_img, 0), Hg - 1);
    int xf = (Wg - 1) - x_img;
    int yf = (Hg - 1) - y_img;
    int cell = (zbin * Wg + xf) * Hg + yf;
    atomicMax(winner + b * NCELL + cell, i);          // last (largest i) wins
}

// feat (b, c=64, n) -> featT (b, n, c=64); 64x64 tiles, float4 on both
// global sides, scalar LDS with pad-65 (2-way bank alias only -> free).
__global__ __launch_bounds__(256) void transpose_k(const float* __restrict__ feat,
                                                   float* __restrict__ featT) {
    __shared__ float tile[64][65];
    int blk = blockIdx.x;
    int b   = blk >> 11;                  // 2048 tiles per batch
    int n0  = (blk & 2047) * 64;
    const float* fb = feat  + (size_t)b * CC * NPTS;
    float*       tb = featT + (size_t)b * NPTS * CC;
    int t = threadIdx.x, w = t >> 6, l = t & 63;
    int sub = l >> 4, m = l & 15;         // 16 lanes per 64-float row
#pragma unroll
    for (int k = 0; k < 4; ++k) {
        int c = k * 16 + w * 4 + sub;     // row of feat
        v4f v = *reinterpret_cast<const v4f*>(fb + (size_t)c * NPTS + n0 + m * 4);
        tile[c][m * 4 + 0] = v.x;
        tile[c][m * 4 + 1] = v.y;
        tile[c][m * 4 + 2] = v.z;
        tile[c][m * 4 + 3] = v.w;
    }
    __syncthreads();
#pragma unroll
    for (int k = 0; k < 4; ++k) {
        int nn = k * 16 + w * 4 + sub;    // row of featT
        v4f v;
        v.x = tile[m * 4 + 0][nn];
        v.y = tile[m * 4 + 1][nn];
        v.z = tile[m * 4 + 2][nn];
        v.w = tile[m * 4 + 3][nn];
        *reinterpret_cast<v4f*>(tb + (size_t)(n0 + nn) * CC + m * 4) = v;
    }
}

// block = (q, b, c): writes out[b][c][q*CPC .. q*CPC+CPC) sequentially.
// blk = q*128 + bc  => the 128 blocks sharing winner chunk q are temporally
// adjacent (winner chunk L2/LLC-resident), and the 16 c-siblings sharing
// each 64B featT line are adjacent too.
__global__ __launch_bounds__(256) void bev_write_k(const float* __restrict__ featT,
                                                   const int*   __restrict__ winner,
                                                   float*       __restrict__ out) {
    int blk = blockIdx.x;
    int q   = blk >> 7;                   // 0..10
    int bc  = blk & 127;                  // b*64 + c
    int b   = bc >> 6;
    int c   = bc & 63;
    int cell0 = q * CPC;

    const int*   wb = winner + b * NCELL + cell0;
    const float* ft = featT + (size_t)b * NPTS * CC + c;      // column c
    float*       ob = out + (size_t)bc * NCELL + cell0;

#pragma unroll 4
    for (int k = threadIdx.x; k < CPC; k += 256) {
        int w = wb[k];
        float v = 0.0f;
        if (w >= 0)                                   // masked: ~11% of lanes
            v = ft[(size_t)w * CC];
        __builtin_nontemporal_store(v, ob + k);       // 256 B/wave, sequential
    }
}

} // namespace

extern "C" void kernel_launch(void* const* d_in, const int* in_sizes, int n_in,
                              void* d_out, int out_size, void* d_ws, size_t ws_size,
                              hipStream_t stream) {
    const float* range_res = (const float*)d_in[0];   // (B,C,RH,RW) f32
    const float* xyz       = (const float*)d_in[1];   // (B,3,RH,RW) f32
    float* out             = (float*)d_out;           // (B,C,D,W,H) f32
    int*   winner          = (int*)d_ws;              // BB*NCELL ints = 5.6 MB
    float* featT           = (float*)((char*)d_ws + (8u << 20));  // 64 MB at +8 MB

    // winner = -1 via byte pattern 0xFF (graph-capturable memset node)
    (void)hipMemsetAsync(winner, 0xFF, (size_t)BB * NCELL * sizeof(int), stream);

    {
        int total = BB * NPTS;
        scatter_winner_k<<<(total + 255) / 256, 256, 0, stream>>>(xyz, winner);
    }
    {
        int blocks = BB * (NPTS / 64);                // 4096
        transpose_k<<<blocks, 256, 0, stream>>>(range_res, featT);
    }
    {
        int blocks = Q * BB * CC;                     // 1408
        bev_write_k<<<blocks, 256, 0, stream>>>(featT, winner, out);
    }
}